// Round 7
// baseline (2016.079 us; speedup 1.0000x reference)
//
#include <hip/hip_runtime.h>
#include <hip/hip_bf16.h>

typedef __attribute__((ext_vector_type(8))) short short8;
typedef __attribute__((ext_vector_type(4))) float f32x4;

#define EPS 1e-5f

__device__ inline unsigned short bf16_rne(float x) {
    unsigned u = __float_as_uint(x);
    unsigned r = u + 0x7FFFu + ((u >> 16) & 1u);
    return (unsigned short)(r >> 16);
}

__device__ inline float sigmoidf_fast(float x) {
    return 1.0f / (1.0f + __expf(-x));
}

__device__ inline float tanhf_fast(float x) {
    float ax = fabsf(x);
    float e = __expf(-2.0f * ax);
    float t = (1.0f - e) / (1.0f + e);
    return copysignf(t, x);
}

// split one 8-float chunk into hi/lo bf16
__device__ inline void cvt8(const float4& a, const float4& b, short8& hi,
                            short8& lo) {
    float vals[8] = {a.x, a.y, a.z, a.w, b.x, b.y, b.z, b.w};
#pragma unroll
    for (int j = 0; j < 8; ++j) {
        unsigned short hb = bf16_rne(vals[j]);
        float fh = __uint_as_float(((unsigned)hb) << 16);
        unsigned short lb = bf16_rne(vals[j] - fh);
        hi[j] = (short)hb;
        lo[j] = (short)lb;
    }
}

// ---------------------------------------------------------------------------
// prep: W1 (K=256 x N=256 f32, row-major [k][n]) -> W_T hi/lo bf16 [n][k]
// ---------------------------------------------------------------------------
__global__ void prep_w(const float* __restrict__ W1,
                       short* __restrict__ WhiT, short* __restrict__ WloT) {
    int n = blockIdx.x;   // 0..255
    int k = threadIdx.x;  // 0..255
    float x = W1[k * 256 + n];
    unsigned short hi = bf16_rne(x);
    float fh = __uint_as_float(((unsigned)hi) << 16);
    unsigned short lo = bf16_rne(x - fh);
    WhiT[n * 256 + k] = (short)hi;
    WloT[n * 256 + k] = (short)lo;
}

// ---------------------------------------------------------------------------
// gemm_stats v4: 512 thr = 8 waves (2 row-halves x 4 col-groups); tile
// 64 rows x 256 cols; K in 2 phases of 128 (node | edge). ALL global A-loads
// issued at kernel top (edge latency hides under phase-0 compute). acc = 32
// VGPR/wave -> target 4 waves/SIMD occupancy (was 2).
// ---------------------------------------------------------------------------
#define COMPUTE_PHASE(KBASE)                                                   \
    _Pragma("unroll") for (int ks = 0; ks < 4; ++ks) {                         \
        short8 ah[2], al[2];                                                   \
        _Pragma("unroll") for (int mt = 0; mt < 2; ++mt) {                     \
            const int row = wr * 32 + mt * 16 + l15;                           \
            const int off = row * 128 + ((ks * 4 + lg) ^ (row & 7)) * 8;       \
            ah[mt] = *(const short8*)(Ahi + off);                              \
            al[mt] = *(const short8*)(Alo + off);                              \
        }                                                                      \
        _Pragma("unroll") for (int nt = 0; nt < 4; ++nt) {                     \
            short8 bh =                                                        \
                *(const short8*)(bbase_hi + nt * 16 * 256 + (KBASE) + ks * 32);\
            short8 bl =                                                        \
                *(const short8*)(bbase_lo + nt * 16 * 256 + (KBASE) + ks * 32);\
            _Pragma("unroll") for (int mt = 0; mt < 2; ++mt) {                 \
                acc[mt][nt] = __builtin_amdgcn_mfma_f32_16x16x32_bf16(         \
                    ah[mt], bh, acc[mt][nt], 0, 0, 0);                         \
                acc[mt][nt] = __builtin_amdgcn_mfma_f32_16x16x32_bf16(         \
                    ah[mt], bl, acc[mt][nt], 0, 0, 0);                         \
                acc[mt][nt] = __builtin_amdgcn_mfma_f32_16x16x32_bf16(         \
                    al[mt], bh, acc[mt][nt], 0, 0, 0);                         \
            }                                                                  \
        }                                                                      \
    }

__global__ __launch_bounds__(512) void gemm_stats(
    const float* __restrict__ node_emb, const float* __restrict__ edge_emb,
    const int* __restrict__ idx,
    const short* __restrict__ WhiT, const short* __restrict__ WloT,
    const float* __restrict__ b1, float* __restrict__ h,
    float* __restrict__ sum1, float* __restrict__ sumsq1) {
    __shared__ __align__(16) short Ahi[64 * 128];  // 16 KB, swizzled chunks
    __shared__ __align__(16) short Alo[64 * 128];  // 16 KB

    const int tid = threadIdx.x;
    const int row0 = blockIdx.x * 64;
    const int r = tid >> 3;  // staging row 0..63 (8 threads/row)
    const int q = tid & 7;   // 16-float chunk within row
    const size_t e = (size_t)row0 + r;
    const float* nodeptr = node_emb + (size_t)idx[e] * 128 + q * 16;
    const float* edgeptr = edge_emb + e * 128 + q * 16;

    // Issue ALL A-loads up front (node consumed first; edge stays in flight
    // through phase-0 compute).
    const float4 n0 = *(const float4*)(nodeptr + 0);
    const float4 n1 = *(const float4*)(nodeptr + 4);
    const float4 n2 = *(const float4*)(nodeptr + 8);
    const float4 n3 = *(const float4*)(nodeptr + 12);
    const float4 e0 = *(const float4*)(edgeptr + 0);
    const float4 e1 = *(const float4*)(edgeptr + 4);
    const float4 e2 = *(const float4*)(edgeptr + 8);
    const float4 e3 = *(const float4*)(edgeptr + 12);

    const int lane = tid & 63;
    const int w = tid >> 6;   // wave 0..7
    const int wr = w & 1;     // row-half (32 rows)
    const int wc = w >> 1;    // col-group (64 cols)
    const int l15 = lane & 15;
    const int lg = lane >> 4;  // 0..3

    f32x4 acc[2][4];
#pragma unroll
    for (int a = 0; a < 2; ++a)
#pragma unroll
        for (int b = 0; b < 4; ++b) acc[a][b] = (f32x4){0.f, 0.f, 0.f, 0.f};

    const short* bbase_hi = WhiT + (wc * 64 + l15) * 256 + lg * 8;
    const short* bbase_lo = WloT + (wc * 64 + l15) * 256 + lg * 8;

    const int off0 = r * 128 + ((2 * q) ^ (r & 7)) * 8;
    const int off1 = r * 128 + ((2 * q + 1) ^ (r & 7)) * 8;

    {   // stage phase 0 (node half)
        short8 h0, l0, h1, l1;
        cvt8(n0, n1, h0, l0);
        cvt8(n2, n3, h1, l1);
        *(short8*)(Ahi + off0) = h0;
        *(short8*)(Alo + off0) = l0;
        *(short8*)(Ahi + off1) = h1;
        *(short8*)(Alo + off1) = l1;
    }
    __syncthreads();

    COMPUTE_PHASE(0)
    __syncthreads();

    {   // stage phase 1 (edge half) — loads completed long ago
        short8 h0, l0, h1, l1;
        cvt8(e0, e1, h0, l0);
        cvt8(e2, e3, h1, l1);
        *(short8*)(Ahi + off0) = h0;
        *(short8*)(Alo + off0) = l0;
        *(short8*)(Ahi + off1) = h1;
        *(short8*)(Alo + off1) = l1;
    }
    __syncthreads();

    COMPUTE_PHASE(128)

    // Epilogue: +bias, store h, per-column stats (C/D: col=l&15, row=lg*4+v)
    const int colbase = wc * 64 + l15;
#pragma unroll
    for (int nt = 0; nt < 4; ++nt) {
        const int col = colbase + nt * 16;
        const float bv = b1[col];
        float s = 0.f, qq = 0.f;
#pragma unroll
        for (int mt = 0; mt < 2; ++mt) {
            const size_t rbase = (size_t)row0 + wr * 32 + mt * 16 + lg * 4;
#pragma unroll
            for (int v = 0; v < 4; ++v) {
                float hv = acc[mt][nt][v] + bv;
                h[(rbase + v) * 256 + col] = hv;
                s += hv;
                qq += hv * hv;
            }
        }
        s += __shfl_xor(s, 16);
        s += __shfl_xor(s, 32);
        qq += __shfl_xor(qq, 16);
        qq += __shfl_xor(qq, 32);
        if (lg == 0) {
            atomicAdd(&sum1[col], s);
            atomicAdd(&sumsq1[col], qq);
        }
    }
}

// ---------------------------------------------------------------------------
// bn1_finalize: fold BN1 into per-column scale/shift (s1t1[0:256]=s, [256:512]=t)
// ---------------------------------------------------------------------------
__global__ void bn1_finalize(const float* __restrict__ sum1,
                             const float* __restrict__ sumsq1,
                             const float* __restrict__ gamma1,
                             const float* __restrict__ beta1,
                             float* __restrict__ s1t1, int E) {
    int c = threadIdx.x;
    float invE = 1.0f / (float)E;
    float mu = sum1[c] * invE;
    float var = sumsq1[c] * invE - mu * mu;
    float s = gamma1[c] * rsqrtf(var + EPS);
    s1t1[c] = s;
    s1t1[256 + c] = beta1[c] - mu * s;
}

// ---------------------------------------------------------------------------
// CSR build: hist -> scan -> fill
// ---------------------------------------------------------------------------
__global__ void csr_hist(const int* __restrict__ idx, int* __restrict__ cnt,
                         int E) {
    int e = blockIdx.x * 256 + threadIdx.x;
    if (e < E) atomicAdd(&cnt[idx[e]], 1);
}

__global__ __launch_bounds__(1024) void csr_scan(const int* __restrict__ cnt,
                                                 int* __restrict__ offs, int N) {
    __shared__ int part[1024];
    const int t = threadIdx.x;
    const int CH = (N + 1023) / 1024;
    const int base = t * CH;
    int s = 0;
    for (int i = 0; i < CH; ++i)
        if (base + i < N) s += cnt[base + i];
    part[t] = s;
    __syncthreads();
    for (int d = 1; d < 1024; d <<= 1) {
        int v = (t >= d) ? part[t - d] : 0;
        __syncthreads();
        part[t] += v;
        __syncthreads();
    }
    int run = (t ? part[t - 1] : 0);
    for (int i = 0; i < CH; ++i) {
        int g = base + i;
        if (g < N) {
            offs[g] = run;
            run += cnt[g];
        }
    }
    if (t == 1023) offs[N] = run;
}

__global__ void csr_fill(const int* __restrict__ idx,
                         const int* __restrict__ offs, int* __restrict__ cursor,
                         int* __restrict__ elist, int E) {
    int e = blockIdx.x * 256 + threadIdx.x;
    if (e < E) {
        int n = idx[e];
        int p = atomicAdd(&cursor[n], 1);
        elist[offs[n] + p] = e;
    }
}

// ---------------------------------------------------------------------------
// gate_gather v2: per node, sum sigmoid(BN(h_f))*tanh(BN(h_c)) over its edges;
// plain store (no atomics). 32 lanes/node, 4 cols/lane, 4 edges in flight.
// ---------------------------------------------------------------------------
__device__ inline void gate_acc(const float4& hf, const float4& hc,
                                const float4& sf, const float4& tf,
                                const float4& sc, const float4& tc, float& a0,
                                float& a1, float& a2, float& a3) {
    a0 += sigmoidf_fast(hf.x * sf.x + tf.x) * tanhf_fast(hc.x * sc.x + tc.x);
    a1 += sigmoidf_fast(hf.y * sf.y + tf.y) * tanhf_fast(hc.y * sc.y + tc.y);
    a2 += sigmoidf_fast(hf.z * sf.z + tf.z) * tanhf_fast(hc.z * sc.z + tc.z);
    a3 += sigmoidf_fast(hf.w * sf.w + tf.w) * tanhf_fast(hc.w * sc.w + tc.w);
}

__global__ __launch_bounds__(256) void gate_gather(
    const float* __restrict__ h, const int* __restrict__ offs,
    const int* __restrict__ elist, const float* __restrict__ s1t1,
    float* __restrict__ agg, int N) {
    const int t = threadIdx.x;
    const int n = blockIdx.x * 8 + (t >> 5);
    const int c = (t & 31) * 4;
    const float4 sf = *(const float4*)(s1t1 + c);
    const float4 tf = *(const float4*)(s1t1 + 256 + c);
    const float4 sc = *(const float4*)(s1t1 + 128 + c);
    const float4 tc = *(const float4*)(s1t1 + 384 + c);
    const int j0 = offs[n];
    const int j1 = offs[n + 1];
    float a0 = 0.f, a1 = 0.f, a2 = 0.f, a3 = 0.f;
    int j = j0;
    for (; j + 4 <= j1; j += 4) {
        const size_t e0 = (size_t)elist[j + 0];
        const size_t e1 = (size_t)elist[j + 1];
        const size_t e2 = (size_t)elist[j + 2];
        const size_t e3 = (size_t)elist[j + 3];
        const float4 f0 = *(const float4*)(h + e0 * 256 + c);
        const float4 c0 = *(const float4*)(h + e0 * 256 + 128 + c);
        const float4 f1 = *(const float4*)(h + e1 * 256 + c);
        const float4 c1 = *(const float4*)(h + e1 * 256 + 128 + c);
        const float4 f2 = *(const float4*)(h + e2 * 256 + c);
        const float4 c2 = *(const float4*)(h + e2 * 256 + 128 + c);
        const float4 f3 = *(const float4*)(h + e3 * 256 + c);
        const float4 c3 = *(const float4*)(h + e3 * 256 + 128 + c);
        gate_acc(f0, c0, sf, tf, sc, tc, a0, a1, a2, a3);
        gate_acc(f1, c1, sf, tf, sc, tc, a0, a1, a2, a3);
        gate_acc(f2, c2, sf, tf, sc, tc, a0, a1, a2, a3);
        gate_acc(f3, c3, sf, tf, sc, tc, a0, a1, a2, a3);
    }
    for (; j < j1; ++j) {
        const size_t e = (size_t)elist[j];
        const float4 hf = *(const float4*)(h + e * 256 + c);
        const float4 hc = *(const float4*)(h + e * 256 + 128 + c);
        gate_acc(hf, hc, sf, tf, sc, tc, a0, a1, a2, a3);
    }
    *(float4*)(agg + (size_t)n * 128 + c) = make_float4(a0, a1, a2, a3);
}

// ---------------------------------------------------------------------------
// bn2_stats: column sums over agg (N x 128)
// ---------------------------------------------------------------------------
__global__ void bn2_stats(const float* __restrict__ agg, float* __restrict__ sum2,
                          float* __restrict__ sumsq2, int N) {
    const int gt = blockIdx.x * blockDim.x + threadIdx.x;
    const int c = (gt & 31) * 4;
    int r = gt >> 5;
    const int rstride = (gridDim.x * blockDim.x) >> 5;
    float s0 = 0, s1 = 0, s2 = 0, s3 = 0, q0 = 0, q1 = 0, q2 = 0, q3 = 0;
    for (; r < N; r += rstride) {
        float4 a = *(const float4*)(agg + (size_t)r * 128 + c);
        s0 += a.x; s1 += a.y; s2 += a.z; s3 += a.w;
        q0 += a.x * a.x; q1 += a.y * a.y; q2 += a.z * a.z; q3 += a.w * a.w;
    }
    atomicAdd(&sum2[c + 0], s0); atomicAdd(&sum2[c + 1], s1);
    atomicAdd(&sum2[c + 2], s2); atomicAdd(&sum2[c + 3], s3);
    atomicAdd(&sumsq2[c + 0], q0); atomicAdd(&sumsq2[c + 1], q1);
    atomicAdd(&sumsq2[c + 2], q2); atomicAdd(&sumsq2[c + 3], q3);
}

// ---------------------------------------------------------------------------
// finalize: out = tanh(node_emb + BN2(agg))
// ---------------------------------------------------------------------------
__global__ void finalize(const float* __restrict__ node,
                         const float* __restrict__ agg,
                         const float* __restrict__ sum2,
                         const float* __restrict__ sumsq2,
                         const float* __restrict__ gamma2,
                         const float* __restrict__ beta2,
                         float* __restrict__ out, int N) {
    const size_t gt = (size_t)blockIdx.x * blockDim.x + threadIdx.x;
    const size_t base = gt * 4;
    if (base >= (size_t)N * 128) return;
    const int c = (int)(base & 127);
    const float invN = 1.0f / (float)N;
    float4 a = *(const float4*)(agg + base);
    float4 x = *(const float4*)(node + base);
    float av[4] = {a.x, a.y, a.z, a.w};
    float xv[4] = {x.x, x.y, x.z, x.w};
    float4 o;
    float ov[4];
#pragma unroll
    for (int j = 0; j < 4; ++j) {
        float mu = sum2[c + j] * invN;
        float var = sumsq2[c + j] * invN - mu * mu;
        float s = gamma2[c + j] * rsqrtf(var + EPS);
        float t = beta2[c + j] - mu * s;
        ov[j] = tanhf_fast(xv[j] + av[j] * s + t);
    }
    o.x = ov[0]; o.y = ov[1]; o.z = ov[2]; o.w = ov[3];
    *(float4*)(out + base) = o;
}

// ---------------------------------------------------------------------------
extern "C" void kernel_launch(void* const* d_in, const int* in_sizes, int n_in,
                              void* d_out, int out_size, void* d_ws, size_t ws_size,
                              hipStream_t stream) {
    const float* node_emb = (const float*)d_in[0];
    const float* edge_emb = (const float*)d_in[1];
    const int* idx = (const int*)d_in[2];
    const float* W1 = (const float*)d_in[3];
    const float* b1 = (const float*)d_in[4];
    const float* gamma1 = (const float*)d_in[5];
    const float* beta1 = (const float*)d_in[6];
    const float* gamma2 = (const float*)d_in[7];
    const float* beta2 = (const float*)d_in[8];
    float* out = (float*)d_out;

    const int E = in_sizes[2];       // 800000
    const int N = in_sizes[0] / 128; // 50000

    // workspace layout
    float* h = (float*)d_ws;                 // E*256
    float* agg = h + (size_t)E * 256;        // N*128
    float* zbase = agg + (size_t)N * 128;    // ---- zeroed region start ----
    float* sum1 = zbase;                     // 256
    float* sumsq1 = sum1 + 256;              // 256
    float* s1t1 = sumsq1 + 256;              // 512
    float* sum2 = s1t1 + 512;                // 128
    float* sumsq2 = sum2 + 128;              // 128
    int* cnt = (int*)(sumsq2 + 128);         // N
    int* cursor = cnt + N;                   // N   ---- zeroed region end ----
    int* offs = cursor + N;                  // N+8 (pad keeps W 16B-aligned)
    int* elist = offs + N + 8;               // E
    short* WhiT = (short*)(elist + E);       // 65536 bf16
    short* WloT = WhiT + 65536;              // 65536 bf16

    const size_t zero_bytes = (size_t)(1280 + 2 * N) * 4;
    hipMemsetAsync(zbase, 0, zero_bytes, stream);

    prep_w<<<256, 256, 0, stream>>>(W1, WhiT, WloT);
    csr_hist<<<(E + 255) / 256, 256, 0, stream>>>(idx, cnt, E);
    csr_scan<<<1, 1024, 0, stream>>>(cnt, offs, N);
    csr_fill<<<(E + 255) / 256, 256, 0, stream>>>(idx, offs, cursor, elist, E);
    gemm_stats<<<E / 64, 512, 0, stream>>>(node_emb, edge_emb, idx, WhiT, WloT,
                                           b1, h, sum1, sumsq1);
    bn1_finalize<<<1, 256, 0, stream>>>(sum1, sumsq1, gamma1, beta1, s1t1, E);
    gate_gather<<<N / 8, 256, 0, stream>>>(h, offs, elist, s1t1, agg, N);
    bn2_stats<<<256, 256, 0, stream>>>(agg, sum2, sumsq2, N);
    finalize<<<(int)(((size_t)N * 128 / 4 + 255) / 256), 256, 0, stream>>>(
        node_emb, agg, sum2, sumsq2, gamma2, beta2, out, N);
}

// Round 8
// 1716.875 us; speedup vs baseline: 1.1743x; 1.1743x over previous
//
#include <hip/hip_runtime.h>
#include <hip/hip_bf16.h>

typedef __attribute__((ext_vector_type(8))) short short8;
typedef __attribute__((ext_vector_type(4))) float f32x4;
typedef __attribute__((ext_vector_type(4))) unsigned short us4;

#define EPS 1e-5f

__device__ inline unsigned short bf16_rne(float x) {
    unsigned u = __float_as_uint(x);
    unsigned r = u + 0x7FFFu + ((u >> 16) & 1u);
    return (unsigned short)(r >> 16);
}

__device__ inline float b2f(unsigned short u) {
    return __uint_as_float(((unsigned)u) << 16);
}

__device__ inline float sigmoidf_fast(float x) {
    return 1.0f / (1.0f + __expf(-x));
}

__device__ inline float tanhf_fast(float x) {
    float ax = fabsf(x);
    float e = __expf(-2.0f * ax);
    float t = (1.0f - e) / (1.0f + e);
    return copysignf(t, x);
}

// ---------------------------------------------------------------------------
// prep: W1 (K=256 x N=256 f32, row-major [k][n]) -> W_T hi/lo bf16 [n][k]
// ---------------------------------------------------------------------------
__global__ void prep_w(const float* __restrict__ W1,
                       short* __restrict__ WhiT, short* __restrict__ WloT) {
    int n = blockIdx.x;   // 0..255
    int k = threadIdx.x;  // 0..255
    float x = W1[k * 256 + n];
    unsigned short hi = bf16_rne(x);
    float fh = __uint_as_float(((unsigned)hi) << 16);
    unsigned short lo = bf16_rne(x - fh);
    WhiT[n * 256 + k] = (short)hi;
    WloT[n * 256 + k] = (short)lo;
}

// ---------------------------------------------------------------------------
// gemm_stats (round-3 v2 structure, known-good): 2-phase full-half-K staging,
// XOR-swizzled LDS, 3 barriers. 256 thr = 4 waves; tile 64 rows x 256 cols.
// Change vs round-3: h stored as bf16 (ushort) — halves h write traffic.
// ---------------------------------------------------------------------------
__global__ __launch_bounds__(256) void gemm_stats(
    const float* __restrict__ node_emb, const float* __restrict__ edge_emb,
    const int* __restrict__ idx,
    const short* __restrict__ WhiT, const short* __restrict__ WloT,
    const float* __restrict__ b1, unsigned short* __restrict__ hh,
    float* __restrict__ sum1, float* __restrict__ sumsq1) {
    __shared__ __align__(16) short Ahi[64 * 128];  // 16 KB, swizzled chunks
    __shared__ __align__(16) short Alo[64 * 128];  // 16 KB

    const int tid = threadIdx.x;
    const int row0 = blockIdx.x * 64;
    const int r = tid >> 2;   // staging row 0..63
    const int q = tid & 3;    // staging quarter (4 chunks of 8 elems)
    const size_t e = (size_t)row0 + r;
    const float* nodeptr = node_emb + (size_t)idx[e] * 128;
    const float* edgeptr = edge_emb + e * 128;

    const int lane = tid & 63;
    const int wid = tid >> 6;
    const int l15 = lane & 15;
    const int lg = lane >> 4;  // 0..3

    f32x4 acc[4][4];
#pragma unroll
    for (int a = 0; a < 4; ++a)
#pragma unroll
        for (int b = 0; b < 4; ++b) acc[a][b] = (f32x4){0.f, 0.f, 0.f, 0.f};

    const short* bbase_hi = WhiT + (wid * 64 + l15) * 256 + lg * 8;
    const short* bbase_lo = WloT + (wid * 64 + l15) * 256 + lg * 8;

#pragma unroll
    for (int ph = 0; ph < 2; ++ph) {
        const float* src = ph ? edgeptr : nodeptr;
        if (ph) __syncthreads();  // phase-0 fragment reads done before restage
#pragma unroll
        for (int cc = 0; cc < 4; ++cc) {
            const int c = q * 4 + cc;  // chunk 0..15 (8 bf16 each)
            const int k0 = c * 8;
            float4 va = *(const float4*)(src + k0);
            float4 vb = *(const float4*)(src + k0 + 4);
            float vals[8] = {va.x, va.y, va.z, va.w, vb.x, vb.y, vb.z, vb.w};
            short8 vhi, vlo;
#pragma unroll
            for (int j = 0; j < 8; ++j) {
                unsigned short hb = bf16_rne(vals[j]);
                float fh = __uint_as_float(((unsigned)hb) << 16);
                unsigned short lb = bf16_rne(vals[j] - fh);
                vhi[j] = (short)hb;
                vlo[j] = (short)lb;
            }
            const int off = r * 128 + (c ^ (r & 7)) * 8;
            *(short8*)(Ahi + off) = vhi;
            *(short8*)(Alo + off) = vlo;
        }
        __syncthreads();

#pragma unroll
        for (int ks = 0; ks < 4; ++ks) {
            short8 ah[4], al[4];
#pragma unroll
            for (int mt = 0; mt < 4; ++mt) {
                const int row = mt * 16 + l15;
                const int off = row * 128 + ((ks * 4 + lg) ^ (row & 7)) * 8;
                ah[mt] = *(const short8*)(Ahi + off);
                al[mt] = *(const short8*)(Alo + off);
            }
            const int kglob = ph * 128 + ks * 32;
#pragma unroll
            for (int nt = 0; nt < 4; ++nt) {
                short8 bh = *(const short8*)(bbase_hi + nt * 16 * 256 + kglob);
                short8 bl = *(const short8*)(bbase_lo + nt * 16 * 256 + kglob);
#pragma unroll
                for (int mt = 0; mt < 4; ++mt) {
                    acc[mt][nt] = __builtin_amdgcn_mfma_f32_16x16x32_bf16(
                        ah[mt], bh, acc[mt][nt], 0, 0, 0);
                    acc[mt][nt] = __builtin_amdgcn_mfma_f32_16x16x32_bf16(
                        ah[mt], bl, acc[mt][nt], 0, 0, 0);
                    acc[mt][nt] = __builtin_amdgcn_mfma_f32_16x16x32_bf16(
                        al[mt], bh, acc[mt][nt], 0, 0, 0);
                }
            }
        }
    }

    // Epilogue: +bias, store h (bf16), per-column f32 stats
    // (C/D: col=l&15, row=lg*4+v)
    const int colbase = wid * 64 + l15;
#pragma unroll
    for (int nt = 0; nt < 4; ++nt) {
        const int col = colbase + nt * 16;
        const float bv = b1[col];
        float s = 0.f, qq = 0.f;
#pragma unroll
        for (int mt = 0; mt < 4; ++mt) {
            const size_t rbase = (size_t)row0 + mt * 16 + lg * 4;
#pragma unroll
            for (int v = 0; v < 4; ++v) {
                float hv = acc[mt][nt][v] + bv;
                hh[(rbase + v) * 256 + col] = bf16_rne(hv);
                s += hv;
                qq += hv * hv;
            }
        }
        s += __shfl_xor(s, 16);
        s += __shfl_xor(s, 32);
        qq += __shfl_xor(qq, 16);
        qq += __shfl_xor(qq, 32);
        if (lg == 0) {
            atomicAdd(&sum1[col], s);
            atomicAdd(&sumsq1[col], qq);
        }
    }
}

// ---------------------------------------------------------------------------
// bn1_finalize: fold BN1 into per-column scale/shift (s1t1[0:256]=s, [256:512]=t)
// ---------------------------------------------------------------------------
__global__ void bn1_finalize(const float* __restrict__ sum1,
                             const float* __restrict__ sumsq1,
                             const float* __restrict__ gamma1,
                             const float* __restrict__ beta1,
                             float* __restrict__ s1t1, int E) {
    int c = threadIdx.x;
    float invE = 1.0f / (float)E;
    float mu = sum1[c] * invE;
    float var = sumsq1[c] * invE - mu * mu;
    float s = gamma1[c] * rsqrtf(var + EPS);
    s1t1[c] = s;
    s1t1[256 + c] = beta1[c] - mu * s;
}

// ---------------------------------------------------------------------------
// CSR build: hist -> scan -> fill (fill now emits per-edge CSR position)
// ---------------------------------------------------------------------------
__global__ void csr_hist(const int* __restrict__ idx, int* __restrict__ cnt,
                         int E) {
    int e = blockIdx.x * 256 + threadIdx.x;
    if (e < E) atomicAdd(&cnt[idx[e]], 1);
}

__global__ __launch_bounds__(1024) void csr_scan(const int* __restrict__ cnt,
                                                 int* __restrict__ offs, int N) {
    __shared__ int part[1024];
    const int t = threadIdx.x;
    const int CH = (N + 1023) / 1024;
    const int base = t * CH;
    int s = 0;
    for (int i = 0; i < CH; ++i)
        if (base + i < N) s += cnt[base + i];
    part[t] = s;
    __syncthreads();
    for (int d = 1; d < 1024; d <<= 1) {
        int v = (t >= d) ? part[t - d] : 0;
        __syncthreads();
        part[t] += v;
        __syncthreads();
    }
    int run = (t ? part[t - 1] : 0);
    for (int i = 0; i < CH; ++i) {
        int g = base + i;
        if (g < N) {
            offs[g] = run;
            run += cnt[g];
        }
    }
    if (t == 1023) offs[N] = run;
}

__global__ void csr_fill(const int* __restrict__ idx,
                         const int* __restrict__ offs, int* __restrict__ cursor,
                         int* __restrict__ epos, int E) {
    int e = blockIdx.x * 256 + threadIdx.x;
    if (e < E) {
        int n = idx[e];
        int p = atomicAdd(&cursor[n], 1);
        epos[e] = offs[n] + p;
    }
}

// ---------------------------------------------------------------------------
// gate_edge: edge-parallel. Coalesced read of h (bf16), gate math, write msg
// row (f32) at CSR position epos[e] — 512 B full-line scatter, no atomics,
// no load-latency chain. 32 lanes per edge, 4 cols per lane.
// ---------------------------------------------------------------------------
__global__ __launch_bounds__(256) void gate_edge(
    const unsigned short* __restrict__ hh, const int* __restrict__ epos,
    const float* __restrict__ s1t1, float* __restrict__ msg, int E) {
    const int t = threadIdx.x;
    const size_t e = (size_t)blockIdx.x * 8 + (t >> 5);
    const int c = (t & 31) * 4;
    const us4 hf = *(const us4*)(hh + e * 256 + c);
    const us4 hc = *(const us4*)(hh + e * 256 + 128 + c);
    const float4 sf = *(const float4*)(s1t1 + c);
    const float4 tf = *(const float4*)(s1t1 + 256 + c);
    const float4 sc = *(const float4*)(s1t1 + 128 + c);
    const float4 tc = *(const float4*)(s1t1 + 384 + c);
    const int p = epos[e];
    float4 m;
    m.x = sigmoidf_fast(b2f(hf[0]) * sf.x + tf.x) * tanhf_fast(b2f(hc[0]) * sc.x + tc.x);
    m.y = sigmoidf_fast(b2f(hf[1]) * sf.y + tf.y) * tanhf_fast(b2f(hc[1]) * sc.y + tc.y);
    m.z = sigmoidf_fast(b2f(hf[2]) * sf.z + tf.z) * tanhf_fast(b2f(hc[2]) * sc.z + tc.z);
    m.w = sigmoidf_fast(b2f(hf[3]) * sf.w + tf.w) * tanhf_fast(b2f(hc[3]) * sc.w + tc.w);
    *(float4*)(msg + (size_t)p * 128 + c) = m;
}

// ---------------------------------------------------------------------------
// seg_sum: agg[n] = sum of msg rows [offs[n], offs[n+1]) — fully streaming
// (blocks process nodes in order == msg memory order). 32 lanes per node.
// ---------------------------------------------------------------------------
__global__ __launch_bounds__(256) void seg_sum(const float* __restrict__ msg,
                                               const int* __restrict__ offs,
                                               float* __restrict__ agg, int N) {
    const int t = threadIdx.x;
    const int n = blockIdx.x * 8 + (t >> 5);
    const int c = (t & 31) * 4;
    const int j0 = offs[n];
    const int j1 = offs[n + 1];
    float a0 = 0.f, a1 = 0.f, a2 = 0.f, a3 = 0.f;
    int j = j0;
    for (; j + 2 <= j1; j += 2) {
        const float4 r0 = *(const float4*)(msg + (size_t)j * 128 + c);
        const float4 r1 = *(const float4*)(msg + (size_t)(j + 1) * 128 + c);
        a0 += r0.x + r1.x;
        a1 += r0.y + r1.y;
        a2 += r0.z + r1.z;
        a3 += r0.w + r1.w;
    }
    if (j < j1) {
        const float4 r0 = *(const float4*)(msg + (size_t)j * 128 + c);
        a0 += r0.x; a1 += r0.y; a2 += r0.z; a3 += r0.w;
    }
    *(float4*)(agg + (size_t)n * 128 + c) = make_float4(a0, a1, a2, a3);
}

// ---------------------------------------------------------------------------
// bn2_stats: column sums over agg (N x 128)
// ---------------------------------------------------------------------------
__global__ void bn2_stats(const float* __restrict__ agg, float* __restrict__ sum2,
                          float* __restrict__ sumsq2, int N) {
    const int gt = blockIdx.x * blockDim.x + threadIdx.x;
    const int c = (gt & 31) * 4;
    int r = gt >> 5;
    const int rstride = (gridDim.x * blockDim.x) >> 5;
    float s0 = 0, s1 = 0, s2 = 0, s3 = 0, q0 = 0, q1 = 0, q2 = 0, q3 = 0;
    for (; r < N; r += rstride) {
        float4 a = *(const float4*)(agg + (size_t)r * 128 + c);
        s0 += a.x; s1 += a.y; s2 += a.z; s3 += a.w;
        q0 += a.x * a.x; q1 += a.y * a.y; q2 += a.z * a.z; q3 += a.w * a.w;
    }
    atomicAdd(&sum2[c + 0], s0); atomicAdd(&sum2[c + 1], s1);
    atomicAdd(&sum2[c + 2], s2); atomicAdd(&sum2[c + 3], s3);
    atomicAdd(&sumsq2[c + 0], q0); atomicAdd(&sumsq2[c + 1], q1);
    atomicAdd(&sumsq2[c + 2], q2); atomicAdd(&sumsq2[c + 3], q3);
}

// ---------------------------------------------------------------------------
// finalize: out = tanh(node_emb + BN2(agg))
// ---------------------------------------------------------------------------
__global__ void finalize(const float* __restrict__ node,
                         const float* __restrict__ agg,
                         const float* __restrict__ sum2,
                         const float* __restrict__ sumsq2,
                         const float* __restrict__ gamma2,
                         const float* __restrict__ beta2,
                         float* __restrict__ out, int N) {
    const size_t gt = (size_t)blockIdx.x * blockDim.x + threadIdx.x;
    const size_t base = gt * 4;
    if (base >= (size_t)N * 128) return;
    const int c = (int)(base & 127);
    const float invN = 1.0f / (float)N;
    float4 a = *(const float4*)(agg + base);
    float4 x = *(const float4*)(node + base);
    float av[4] = {a.x, a.y, a.z, a.w};
    float xv[4] = {x.x, x.y, x.z, x.w};
    float4 o;
    float ov[4];
#pragma unroll
    for (int j = 0; j < 4; ++j) {
        float mu = sum2[c + j] * invN;
        float var = sumsq2[c + j] * invN - mu * mu;
        float s = gamma2[c + j] * rsqrtf(var + EPS);
        float t = beta2[c + j] - mu * s;
        ov[j] = tanhf_fast(xv[j] + av[j] * s + t);
    }
    o.x = ov[0]; o.y = ov[1]; o.z = ov[2]; o.w = ov[3];
    *(float4*)(out + base) = o;
}

// ---------------------------------------------------------------------------
extern "C" void kernel_launch(void* const* d_in, const int* in_sizes, int n_in,
                              void* d_out, int out_size, void* d_ws, size_t ws_size,
                              hipStream_t stream) {
    const float* node_emb = (const float*)d_in[0];
    const float* edge_emb = (const float*)d_in[1];
    const int* idx = (const int*)d_in[2];
    const float* W1 = (const float*)d_in[3];
    const float* b1 = (const float*)d_in[4];
    const float* gamma1 = (const float*)d_in[5];
    const float* beta1 = (const float*)d_in[6];
    const float* gamma2 = (const float*)d_in[7];
    const float* beta2 = (const float*)d_in[8];
    float* out = (float*)d_out;

    const int E = in_sizes[2];       // 800000
    const int N = in_sizes[0] / 128; // 50000

    // workspace layout
    unsigned short* hh = (unsigned short*)d_ws;            // E*256 bf16 (512B/row)
    float* msg = (float*)((char*)d_ws + (size_t)E * 512);  // E*128 f32
    float* agg = msg + (size_t)E * 128;                    // N*128
    float* zbase = agg + (size_t)N * 128;  // ---- zeroed region start ----
    float* sum1 = zbase;                   // 256
    float* sumsq1 = sum1 + 256;            // 256
    float* s1t1 = sumsq1 + 256;            // 512
    float* sum2 = s1t1 + 512;              // 128
    float* sumsq2 = sum2 + 128;            // 128
    int* cnt = (int*)(sumsq2 + 128);       // N
    int* cursor = cnt + N;                 // N   ---- zeroed region end ----
    int* offs = cursor + N;                // N+1 (+pad)
    int* epos = offs + N + 8;              // E
    short* WhiT = (short*)(epos + E);      // 65536 bf16
    short* WloT = WhiT + 65536;            // 65536 bf16

    const size_t zero_bytes = (size_t)(1280 + 2 * N) * 4;
    hipMemsetAsync(zbase, 0, zero_bytes, stream);

    prep_w<<<256, 256, 0, stream>>>(W1, WhiT, WloT);
    csr_hist<<<(E + 255) / 256, 256, 0, stream>>>(idx, cnt, E);
    csr_scan<<<1, 1024, 0, stream>>>(cnt, offs, N);
    csr_fill<<<(E + 255) / 256, 256, 0, stream>>>(idx, offs, cursor, epos, E);
    gemm_stats<<<E / 64, 256, 0, stream>>>(node_emb, edge_emb, idx, WhiT, WloT,
                                           b1, hh, sum1, sumsq1);
    bn1_finalize<<<1, 256, 0, stream>>>(sum1, sumsq1, gamma1, beta1, s1t1, E);
    gate_edge<<<E / 8, 256, 0, stream>>>(hh, epos, s1t1, msg, E);
    seg_sum<<<N / 8, 256, 0, stream>>>(msg, offs, agg, N);
    bn2_stats<<<256, 256, 0, stream>>>(agg, sum2, sumsq2, N);
    finalize<<<(int)(((size_t)N * 128 / 4 + 255) / 256), 256, 0, stream>>>(
        node_emb, agg, sum2, sumsq2, gamma2, beta2, out, N);
}